// Round 4
// baseline (454.194 us; speedup 1.0000x reference)
//
#include <hip/hip_runtime.h>
#include <hip/hip_bf16.h>
#include <math.h>

// Problem constants (fixed by the reference's setup_inputs)
#define BB 4
#define TT 2048
#define DD 384
#define HH 192
#define TOTAL_LEN 65536                 // B*T*8 (static output length)
#define EXP_ELEMS (BB * TOTAL_LEN * DD) // 100,663,296 floats
#define F4_PER_ROW (DD / 4)             // 96
#define TOTAL_F4 (BB * TOTAL_LEN * F4_PER_ROW) // 25,165,824
#define ROWS_PER_BLK 8                  // MLP rows per block

typedef float f32x4 __attribute__((ext_vector_type(4)));

// ---------------------------------------------------------------------------
// K1: 2-layer MLP duration head. 1024 blocks x 192 threads (3 waves, none
// idle). Block stages 8 x-rows in LDS (12 KB); thread j owns h-column j.
// ~40 VGPRs, 4+ blocks/CU.
// ---------------------------------------------------------------------------
__global__ __launch_bounds__(192) void mlp_dur_kernel(
    const float* __restrict__ x, const float* __restrict__ w1,
    const float* __restrict__ b1, const float* __restrict__ w2,
    const float* __restrict__ b2, float* __restrict__ dur_out,
    int* __restrict__ dur0) {
  __shared__ float xs[ROWS_PER_BLK * DD]; // 12 KB
  __shared__ float part[ROWS_PER_BLK * 3];

  const int tid = threadIdx.x;
  const int lane = tid & 63;
  const int wave = tid >> 6;
  const int row0 = blockIdx.x * ROWS_PER_BLK;

  // Stage 8 rows (768 float4) coalesced into LDS: 4 f4 per thread.
  const f32x4* xg = (const f32x4*)(x + (size_t)row0 * DD);
  f32x4* xs4 = (f32x4*)xs;
#pragma unroll
  for (int i = 0; i < 4; ++i) xs4[i * 192 + tid] = xg[i * 192 + tid];
  __syncthreads();

  float acc[ROWS_PER_BLK];
#pragma unroll
  for (int r = 0; r < ROWS_PER_BLK; ++r) acc[r] = 0.f;

  const int j = tid; // 0..191, all active
  for (int k = 0; k < DD; k += 4) {
    float w[4];
#pragma unroll
    for (int kk = 0; kk < 4; ++kk) w[kk] = w1[(size_t)(k + kk) * HH + j];
#pragma unroll
    for (int r = 0; r < ROWS_PER_BLK; ++r) {
      const f32x4 xv = *(const f32x4*)(xs + r * DD + k); // broadcast b128
#pragma unroll
      for (int kk = 0; kk < 4; ++kk) acc[r] = fmaf(xv[kk], w[kk], acc[r]);
    }
  }

  const float b1v = b1[j];
  const float w2v = w2[j];

#pragma unroll
  for (int r = 0; r < ROWS_PER_BLK; ++r) {
    float s = fmaxf(acc[r] + b1v, 0.f) * w2v;
#pragma unroll
    for (int off = 32; off > 0; off >>= 1) s += __shfl_down(s, off, 64);
    if (lane == 0) part[r * 3 + wave] = s;
  }
  __syncthreads();

  if (tid < ROWS_PER_BLK) {
    const float z = part[tid * 3] + part[tid * 3 + 1] + part[tid * 3 + 2] + b2[0];
    const float sp = fmaxf(z, 0.f) + log1pf(expf(-fabsf(z))); // stable softplus
    const float dur = rintf(fmaxf(sp, 8.0f)); // round-half-even == jnp.round
    const int row = row0 + tid;
    dur_out[row] = dur;
    if (row < TT) dur0[row] = (int)dur; // batch-0 durations drive expansion
  }
}

// ---------------------------------------------------------------------------
// K2: inclusive scan of dur0[2048] -> cum[2048]. One block, 256 threads x 8.
// ---------------------------------------------------------------------------
__global__ __launch_bounds__(256) void scan_kernel(const int* __restrict__ dur0,
                                                   int* __restrict__ cum) {
  __shared__ int lds[256];
  const int tid = threadIdx.x;
  const int base = tid * 8;
  int v[8];
  int run = 0;
#pragma unroll
  for (int i = 0; i < 8; ++i) {
    run += dur0[base + i];
    v[i] = run;
  }
  lds[tid] = run;
  __syncthreads();
  for (int off = 1; off < 256; off <<= 1) {
    const int t = (tid >= off) ? lds[tid - off] : 0;
    __syncthreads();
    lds[tid] += t;
    __syncthreads();
  }
  const int excl = lds[tid] - run;
#pragma unroll
  for (int i = 0; i < 8; ++i) cum[base + i] = v[i] + excl;
}

// ---------------------------------------------------------------------------
// K3: idx_map by scatter-inversion (no binary search).
// Thread i < T writes idx_map[cum[i]-dur..cum[i]) = i  (valid region, exactly
// covers [0, total)). Every thread i with i >= total writes idx_map[i] = -1
// (invalid tail). Regions are disjoint and jointly cover [0, TOTAL_LEN).
// 65536 threads; ~256 KB of writes total.
// ---------------------------------------------------------------------------
__global__ __launch_bounds__(256) void idx_scatter_kernel(
    const int* __restrict__ dur0, const int* __restrict__ cum,
    int* __restrict__ idx_map) {
  const int i = blockIdx.x * 256 + threadIdx.x;
  const int total = min(cum[TT - 1], TOTAL_LEN);
  if (i >= total) idx_map[i] = -1;
  if (i < TT) {
    const int end = min(cum[i], TOTAL_LEN);
    const int start = min(end, max(cum[i] - dur0[i], 0));
    for (int p = start; p < end; ++p) idx_map[p] = i;
  }
}

// ---------------------------------------------------------------------------
// K4: expansion. 4 f32x4 per thread, grid-strided (each chunk coalesced),
// nontemporal stores. out[b, pos, :] = (idx>=0) ? x[b, idx, :] : 0
// ---------------------------------------------------------------------------
#define EXP_STRIDE (TOTAL_F4 / 4) // 6,291,456 threads
__global__ __launch_bounds__(256) void expand_kernel(
    const f32x4* __restrict__ x4, const int* __restrict__ idx_map,
    f32x4* __restrict__ out4) {
  const unsigned t = blockIdx.x * 256u + threadIdx.x;
#pragma unroll
  for (int i = 0; i < 4; ++i) {
    const unsigned e = t + (unsigned)i * EXP_STRIDE;
    const unsigned row = e / 96u; // magic-mul division
    const unsigned col = e - row * 96u;
    const unsigned b = row >> 16; // TOTAL_LEN = 65536
    const unsigned pos = row & 65535u;
    const int id = idx_map[pos]; // broadcast across the 96 lanes of a row
    f32x4 v = {0.f, 0.f, 0.f, 0.f};
    if (id >= 0) v = x4[((size_t)b * TT + (unsigned)id) * F4_PER_ROW + col];
    __builtin_nontemporal_store(v, out4 + e);
  }
}

extern "C" void kernel_launch(void* const* d_in, const int* in_sizes, int n_in,
                              void* d_out, int out_size, void* d_ws,
                              size_t ws_size, hipStream_t stream) {
  const float* x = (const float*)d_in[0];
  const float* w1 = (const float*)d_in[1];
  const float* b1 = (const float*)d_in[2];
  const float* w2 = (const float*)d_in[3];
  const float* b2 = (const float*)d_in[4];
  // d_in[5] = total_length scalar; static (65536) by construction.

  float* out = (float*)d_out;
  float* dur_out = out + (size_t)EXP_ELEMS; // output 1: (B, T) durations

  int* ws = (int*)d_ws;
  int* dur0 = ws;             // 2048 ints
  int* cum = ws + TT;         // 2048 ints
  int* idx_map = ws + 2 * TT; // 65536 ints

  mlp_dur_kernel<<<TT * BB / ROWS_PER_BLK, 192, 0, stream>>>(x, w1, b1, w2, b2,
                                                             dur_out, dur0);
  scan_kernel<<<1, 256, 0, stream>>>(dur0, cum);
  idx_scatter_kernel<<<TOTAL_LEN / 256, 256, 0, stream>>>(dur0, cum, idx_map);
  expand_kernel<<<EXP_STRIDE / 256, 256, 0, stream>>>((const f32x4*)x, idx_map,
                                                      (f32x4*)out);
}